// Round 1
// baseline (3699.276 us; speedup 1.0000x reference)
//
#include <hip/hip_runtime.h>
#include <cstddef>

#define Bn 128
#define Tn 2048
#define Vn 128
#define An 10
#define Hn 64
#define NCn 4000
#define STEPSn 32
#define BDIM 1024
#define NWAVES 16

__device__ __forceinline__ float waveReduceSum(float v) {
    #pragma unroll
    for (int off = 32; off > 0; off >>= 1) v += __shfl_xor(v, off, 64);
    return v;
}
__device__ __forceinline__ float waveReduceMax(float v) {
    #pragma unroll
    for (int off = 32; off > 0; off >>= 1) v = fmaxf(v, __shfl_xor(v, off, 64));
    return v;
}

// Block-wide reductions over 16 waves. All 1024 threads must call.
__device__ __forceinline__ float blockReduceMax(float v, float* red) {
    v = waveReduceMax(v);
    __syncthreads();                      // protect red from previous use
    if ((threadIdx.x & 63) == 0) red[threadIdx.x >> 6] = v;
    __syncthreads();
    float r = red[0];
    #pragma unroll
    for (int i = 1; i < NWAVES; ++i) r = fmaxf(r, red[i]);
    return r;
}
__device__ __forceinline__ float blockReduceSum(float v, float* red) {
    v = waveReduceSum(v);
    __syncthreads();
    if ((threadIdx.x & 63) == 0) red[threadIdx.x >> 6] = v;
    __syncthreads();
    float r = 0.f;
    #pragma unroll
    for (int i = 0; i < NWAVES; ++i) r += red[i];
    return r;
}

// One-time: v_proj[b,t,a] = sum_v enc[b,t,v] * wv[a,v]
__global__ __launch_bounds__(256) void vproj_kernel(const float* __restrict__ enc,
                                                    const float* __restrict__ wv,
                                                    float* __restrict__ vp) {
    int idx = blockIdx.x * 256 + threadIdx.x;      // (b*T+t)*A + a
    if (idx >= Bn * Tn * An) return;
    int bt = idx / An;
    int a  = idx - bt * An;
    const float4* e = (const float4*)(enc + (size_t)bt * Vn);
    const float4* w = (const float4*)(wv + a * Vn);
    float acc = 0.f;
    #pragma unroll
    for (int k = 0; k < Vn / 4; ++k) {
        float4 ev = e[k], wvv = w[k];
        acc += ev.x * wvv.x + ev.y * wvv.y + ev.z * wvv.z + ev.w * wvv.w;
    }
    vp[idx] = acc;
}

__global__ __launch_bounds__(BDIM) void decoder_kernel(
    const float* __restrict__ enc,      // (B,T,V)
    const float* __restrict__ w_hh0,    // (192,64)
    const float* __restrict__ b_ih0, const float* __restrict__ b_hh0,
    const float* __restrict__ w_ih1, const float* __restrict__ w_hh1,
    const float* __restrict__ b_ih1, const float* __restrict__ b_hh1,
    const float* __restrict__ conv_w,   // (10,3)
    const float* __restrict__ conv_b,
    const float* __restrict__ wq,       // (10,64)
    const float* __restrict__ bq,
    const float* __restrict__ attn_bias,
    const float* __restrict__ score_w, const float* __restrict__ score_b,
    const float* __restrict__ fc_w1, const float* __restrict__ fc_b1,
    const float* __restrict__ fc_w2, const float* __restrict__ fc_b2,
    const float* __restrict__ fc_w3, const float* __restrict__ fc_b3,
    const float* __restrict__ vp,       // (B,T,A)
    float* __restrict__ out_logp,       // (B,STEPS,NC)
    float* __restrict__ out_attn)       // (B,STEPS,T)
{
    const int b   = blockIdx.x;
    const int tid = threadIdx.x;

    __shared__ float la[2][Tn];          // 16 KB attention double buffer
    __shared__ float h0s[Hn], h1s[Hn], h0n[Hn], h1n[Hn];
    __shared__ float g0[192], g1i[192], g1h[192];
    __shared__ float qq[16];
    __shared__ float part[16][Vn];       // 8 KB context partials
    __shared__ float ctx[Vn];
    __shared__ float hcat[192];
    __shared__ float y1[96], y2[48];
    __shared__ float red[NWAVES];

    // init state
    for (int i = tid; i < Tn; i += BDIM) { la[0][i] = 0.f; la[1][i] = 0.f; }
    if (tid < Hn) { h0s[tid] = 0.f; h1s[tid] = 0.f; }
    __syncthreads();

    const float sb = score_b[0];
    int cur = 0;

    for (int s = 0; s < STEPSn; ++s) {
        // ---- GRU layer 0 (input x0 == 0 -> gi = b_ih0) ----
        if (tid < 192) {
            float acc = b_hh0[tid];
            const float4* wr = (const float4*)(w_hh0 + tid * Hn);
            #pragma unroll
            for (int k = 0; k < Hn / 4; ++k) {
                float4 w = wr[k];
                acc += w.x * h0s[4*k] + w.y * h0s[4*k+1] + w.z * h0s[4*k+2] + w.w * h0s[4*k+3];
            }
            g0[tid] = acc;
        }
        __syncthreads();
        if (tid < Hn) {
            float r = 1.f / (1.f + __expf(-(b_ih0[tid]       + g0[tid])));
            float z = 1.f / (1.f + __expf(-(b_ih0[64 + tid]  + g0[64 + tid])));
            float n = tanhf(b_ih0[128 + tid] + r * g0[128 + tid]);
            h0n[tid] = (1.f - z) * n + z * h0s[tid];
        }
        __syncthreads();

        // ---- GRU layer 1 ----
        if (tid < 192) {
            float acc = b_ih1[tid];
            const float4* wr = (const float4*)(w_ih1 + tid * Hn);
            #pragma unroll
            for (int k = 0; k < Hn / 4; ++k) {
                float4 w = wr[k];
                acc += w.x * h0n[4*k] + w.y * h0n[4*k+1] + w.z * h0n[4*k+2] + w.w * h0n[4*k+3];
            }
            g1i[tid] = acc;
        } else if (tid >= 256 && tid < 448) {
            int j = tid - 256;
            float acc = b_hh1[j];
            const float4* wr = (const float4*)(w_hh1 + j * Hn);
            #pragma unroll
            for (int k = 0; k < Hn / 4; ++k) {
                float4 w = wr[k];
                acc += w.x * h1s[4*k] + w.y * h1s[4*k+1] + w.z * h1s[4*k+2] + w.w * h1s[4*k+3];
            }
            g1h[j] = acc;
        }
        __syncthreads();
        if (tid < Hn) {
            float r = 1.f / (1.f + __expf(-(g1i[tid]      + g1h[tid])));
            float z = 1.f / (1.f + __expf(-(g1i[64 + tid] + g1h[64 + tid])));
            float n = tanhf(g1i[128 + tid] + r * g1h[128 + tid]);
            h1n[tid] = (1.f - z) * n + z * h1s[tid];
        }
        __syncthreads();

        // ---- commit state, query projection ----
        if (tid < Hn) { h0s[tid] = h0n[tid]; h1s[tid] = h1n[tid]; }
        if (tid >= 128 && tid < 128 + An) {
            int a = tid - 128;
            float acc = bq[a] + attn_bias[a];
            const float* wr = wq + a * Hn;
            #pragma unroll
            for (int k = 0; k < Hn; ++k) acc += wr[k] * h1n[k];
            qq[a] = acc;
        }
        __syncthreads();

        // ---- score + softmax over T (each thread owns t and t+1024) ----
        float sc[2];
        const float* vpb = vp + (size_t)b * Tn * An;
        #pragma unroll
        for (int i = 0; i < 2; ++i) {
            int t = tid + i * BDIM;
            float lm1 = (t > 0)      ? la[cur][t - 1] : 0.f;
            float l0  =                la[cur][t];
            float lp1 = (t < Tn - 1) ? la[cur][t + 1] : 0.f;
            float ssum = sb;
            const float* vpt = vpb + (size_t)t * An;
            #pragma unroll
            for (int a = 0; a < An; ++a) {
                float loc = conv_w[a*3+0]*lm1 + conv_w[a*3+1]*l0 + conv_w[a*3+2]*lp1 + conv_b[a];
                float e = tanhf(qq[a] + vpt[a] + loc);
                ssum += score_w[a] * e;
            }
            sc[i] = ssum;
        }
        float m   = blockReduceMax(fmaxf(sc[0], sc[1]), red);
        float p0  = __expf(sc[0] - m), p1 = __expf(sc[1] - m);
        float tot = blockReduceSum(p0 + p1, red);
        float inv = 1.f / tot;
        int nxt = cur ^ 1;
        {
            float a0 = p0 * inv, a1 = p1 * inv;
            la[nxt][tid]        = a0;
            la[nxt][tid + BDIM] = a1;
            float* oa = out_attn + ((size_t)b * STEPSn + s) * Tn;
            oa[tid]        = a0;
            oa[tid + BDIM] = a1;
        }
        __syncthreads();

        // ---- context[v] = sum_t attn[t] * enc[b,t,v] ----
        {
            const float* lac = la[nxt];
            int v2 = tid & 63, g = tid >> 6;    // one wave per group g
            const float2* enc2 = (const float2*)(enc + (size_t)b * Tn * Vn);
            float ax = 0.f, ay = 0.f;
            for (int t = g; t < Tn; t += 16) {
                float a = lac[t];
                float2 e = enc2[t * 64 + v2];
                ax += a * e.x; ay += a * e.y;
            }
            part[g][2 * v2]     = ax;
            part[g][2 * v2 + 1] = ay;
        }
        __syncthreads();
        if (tid < Vn) {
            float s2 = 0.f;
            #pragma unroll
            for (int g2 = 0; g2 < 16; ++g2) s2 += part[g2][tid];
            ctx[tid] = s2;
        }
        __syncthreads();

        // ---- classifier MLP ----
        if (tid < Hn) hcat[tid] = h1n[tid];
        else if (tid < 192) hcat[tid] = ctx[tid - Hn];
        __syncthreads();
        if (tid < 96) {
            float acc = fc_b1[tid];
            const float4* wr = (const float4*)(fc_w1 + tid * 192);
            #pragma unroll
            for (int k = 0; k < 48; ++k) {
                float4 w = wr[k];
                acc += w.x*hcat[4*k] + w.y*hcat[4*k+1] + w.z*hcat[4*k+2] + w.w*hcat[4*k+3];
            }
            y1[tid] = fmaxf(acc, 0.f);
        }
        __syncthreads();
        if (tid < 48) {
            float acc = fc_b2[tid];
            const float4* wr = (const float4*)(fc_w2 + tid * 96);
            #pragma unroll
            for (int k = 0; k < 24; ++k) {
                float4 w = wr[k];
                acc += w.x*y1[4*k] + w.y*y1[4*k+1] + w.z*y1[4*k+2] + w.w*y1[4*k+3];
            }
            y2[tid] = fmaxf(acc, 0.f);
        }
        __syncthreads();

        // ---- logits (4000) + log_softmax ----
        float lg[4];
        float lmax = -INFINITY;
        #pragma unroll
        for (int i = 0; i < 4; ++i) {
            int c = tid + i * BDIM;
            if (c < NCn) {
                float acc = fc_b3[c];
                const float4* wr = (const float4*)(fc_w3 + (size_t)c * 48);
                #pragma unroll
                for (int j = 0; j < 12; ++j) {
                    float4 w = wr[j];
                    acc += w.x*y2[4*j] + w.y*y2[4*j+1] + w.z*y2[4*j+2] + w.w*y2[4*j+3];
                }
                lg[i] = acc;
                lmax = fmaxf(lmax, acc);
            } else {
                lg[i] = -INFINITY;
            }
        }
        float m2 = blockReduceMax(lmax, red);
        float es = 0.f;
        #pragma unroll
        for (int i = 0; i < 4; ++i) {
            int c = tid + i * BDIM;
            if (c < NCn) es += __expf(lg[i] - m2);
        }
        float tot2 = blockReduceSum(es, red);
        float lse = m2 + logf(tot2);
        float* op = out_logp + ((size_t)b * STEPSn + s) * NCn;
        #pragma unroll
        for (int i = 0; i < 4; ++i) {
            int c = tid + i * BDIM;
            if (c < NCn) op[c] = lg[i] - lse;
        }

        cur = nxt;
        __syncthreads();
    }
}

extern "C" void kernel_launch(void* const* d_in, const int* in_sizes, int n_in,
                              void* d_out, int out_size, void* d_ws, size_t ws_size,
                              hipStream_t stream) {
    const float* enc    = (const float*)d_in[0];
    // d_in[1] = rnn_w_ih0 — unused (x0 == 0)
    const float* w_hh0  = (const float*)d_in[2];
    const float* b_ih0  = (const float*)d_in[3];
    const float* b_hh0  = (const float*)d_in[4];
    const float* w_ih1  = (const float*)d_in[5];
    const float* w_hh1  = (const float*)d_in[6];
    const float* b_ih1  = (const float*)d_in[7];
    const float* b_hh1  = (const float*)d_in[8];
    const float* conv_w = (const float*)d_in[9];
    const float* conv_b = (const float*)d_in[10];
    const float* wq     = (const float*)d_in[11];
    const float* bq     = (const float*)d_in[12];
    const float* wv     = (const float*)d_in[13];
    const float* abias  = (const float*)d_in[14];
    const float* sw     = (const float*)d_in[15];
    const float* sb     = (const float*)d_in[16];
    const float* fc_w1  = (const float*)d_in[17];
    const float* fc_b1  = (const float*)d_in[18];
    const float* fc_w2  = (const float*)d_in[19];
    const float* fc_b2  = (const float*)d_in[20];
    const float* fc_w3  = (const float*)d_in[21];
    const float* fc_b3  = (const float*)d_in[22];

    float* vp = (float*)d_ws;                         // (B,T,A) fp32 = 10.5 MB
    float* out_logp = (float*)d_out;                  // (B,32,4000)
    float* out_attn = out_logp + (size_t)Bn * STEPSn * NCn;  // (B,32,2048)

    int total = Bn * Tn * An;
    vproj_kernel<<<(total + 255) / 256, 256, 0, stream>>>(enc, wv, vp);

    decoder_kernel<<<Bn, BDIM, 0, stream>>>(
        enc, w_hh0, b_ih0, b_hh0, w_ih1, w_hh1, b_ih1, b_hh1,
        conv_w, conv_b, wq, bq, abias, sw, sb,
        fc_w1, fc_b1, fc_w2, fc_b2, fc_w3, fc_b3,
        vp, out_logp, out_attn);
}

// Round 3
// 1689.304 us; speedup vs baseline: 2.1898x; 2.1898x over previous
//
#include <hip/hip_runtime.h>
#include <cstddef>

#define Bn 128
#define Tn 2048
#define Vn 128
#define An 10
#define Hn 64
#define NCn 4000
#define STEPSn 32
#define SLICE 256
#define NQ 8           // Tn / SLICE

__device__ __forceinline__ float waveReduceSum(float v) {
    #pragma unroll
    for (int off = 32; off > 0; off >>= 1) v += __shfl_xor(v, off, 64);
    return v;
}

__device__ __forceinline__ unsigned short f2bf(float f) {
    unsigned u = __float_as_uint(f);
    u += 0x7fffu + ((u >> 16) & 1u);
    return (unsigned short)(u >> 16);
}

// ---------- one-time: v_proj[b,t,a] = sum_v enc[b,t,v] * wv[a,v] ----------
__global__ __launch_bounds__(256) void vproj_kernel(const float* __restrict__ enc,
                                                    const float* __restrict__ wv,
                                                    float* __restrict__ vp) {
    int idx = blockIdx.x * 256 + threadIdx.x;      // (b*T+t)*A + a
    if (idx >= Bn * Tn * An) return;
    int bt = idx / An;
    int a  = idx - bt * An;
    const float4* e = (const float4*)(enc + (size_t)bt * Vn);
    const float4* w = (const float4*)(wv + a * Vn);
    float acc = 0.f;
    #pragma unroll
    for (int k = 0; k < Vn / 4; ++k) {
        float4 ev = e[k], wvv = w[k];
        acc += ev.x * wvv.x + ev.y * wvv.y + ev.z * wvv.z + ev.w * wvv.w;
    }
    vp[idx] = acc;
}

// ---------- one-time: enc fp32 -> bf16 ----------
__global__ __launch_bounds__(256) void tobf16_kernel(const float* __restrict__ in,
                                                     unsigned short* __restrict__ out) {
    size_t i = ((size_t)blockIdx.x * 256 + threadIdx.x) * 4;
    float4 v = *(const float4*)(in + i);
    ushort4 o;
    o.x = f2bf(v.x); o.y = f2bf(v.y); o.z = f2bf(v.z); o.w = f2bf(v.w);
    *(ushort4*)(out + i) = o;
}

// ---------- one-time: GRU trajectory (independent of attention; x0 == 0) ----------
__global__ __launch_bounds__(256) void gru_traj_kernel(
    const float* __restrict__ w_hh0, const float* __restrict__ b_ih0, const float* __restrict__ b_hh0,
    const float* __restrict__ w_ih1, const float* __restrict__ w_hh1,
    const float* __restrict__ b_ih1, const float* __restrict__ b_hh1,
    const float* __restrict__ wq, const float* __restrict__ bq, const float* __restrict__ abias,
    float* __restrict__ h1_all, float* __restrict__ qq_all)
{
    __shared__ float h0[Hn], h1[Hn], h0n[Hn], h1n[Hn], g0[192], g1i[192], g1h[192];
    int tid = threadIdx.x;
    if (tid < Hn) { h0[tid] = 0.f; h1[tid] = 0.f; }
    __syncthreads();
    for (int s = 0; s < STEPSn; ++s) {
        if (tid < 192) {
            float acc = b_hh0[tid];
            const float4* wr = (const float4*)(w_hh0 + tid * Hn);
            #pragma unroll
            for (int k = 0; k < Hn / 4; ++k) {
                float4 w = wr[k];
                acc += w.x*h0[4*k] + w.y*h0[4*k+1] + w.z*h0[4*k+2] + w.w*h0[4*k+3];
            }
            g0[tid] = acc;
        }
        __syncthreads();
        if (tid < Hn) {
            float r = 1.f / (1.f + __expf(-(b_ih0[tid]      + g0[tid])));
            float z = 1.f / (1.f + __expf(-(b_ih0[64 + tid] + g0[64 + tid])));
            float n = tanhf(b_ih0[128 + tid] + r * g0[128 + tid]);
            h0n[tid] = (1.f - z) * n + z * h0[tid];
        }
        __syncthreads();
        if (tid < 192) {
            float acc = b_ih1[tid];
            const float4* wr = (const float4*)(w_ih1 + tid * Hn);
            #pragma unroll
            for (int k = 0; k < Hn / 4; ++k) {
                float4 w = wr[k];
                acc += w.x*h0n[4*k] + w.y*h0n[4*k+1] + w.z*h0n[4*k+2] + w.w*h0n[4*k+3];
            }
            g1i[tid] = acc;
            float acc2 = b_hh1[tid];
            const float4* wr2 = (const float4*)(w_hh1 + tid * Hn);
            #pragma unroll
            for (int k = 0; k < Hn / 4; ++k) {
                float4 w = wr2[k];
                acc2 += w.x*h1[4*k] + w.y*h1[4*k+1] + w.z*h1[4*k+2] + w.w*h1[4*k+3];
            }
            g1h[tid] = acc2;
        }
        __syncthreads();
        if (tid < Hn) {
            float r = 1.f / (1.f + __expf(-(g1i[tid]      + g1h[tid])));
            float z = 1.f / (1.f + __expf(-(g1i[64 + tid] + g1h[64 + tid])));
            float n = tanhf(g1i[128 + tid] + r * g1h[128 + tid]);
            h1n[tid] = (1.f - z) * n + z * h1[tid];
        }
        __syncthreads();
        if (tid < Hn) {
            h0[tid] = h0n[tid];
            float v = h1n[tid];
            h1[tid] = v;
            h1_all[s * Hn + tid] = v;
        }
        __syncthreads();
        if (tid < An) {
            float acc = bq[tid] + abias[tid];
            const float* wr = wq + tid * Hn;
            #pragma unroll
            for (int k = 0; k < Hn; ++k) acc += wr[k] * h1n[k];
            qq_all[s * 16 + tid] = acc;
        }
        __syncthreads();
    }
}

// ---------- per-step: score -> exp -> partial sums + unnormalized context ----------
__global__ __launch_bounds__(256) void attn_step_kernel(
    const float* __restrict__ enc, const unsigned short* __restrict__ enc16, int use16,
    const float* __restrict__ vp, const float* __restrict__ qq_all,
    const float* __restrict__ conv_w, const float* __restrict__ conv_b,
    const float* __restrict__ score_w, const float* __restrict__ score_b,
    float* __restrict__ psum_all, float* __restrict__ ctx_all,
    float* __restrict__ out_attn, int s)
{
    const int b = blockIdx.x >> 3, q = blockIdx.x & 7;
    const int tid = threadIdx.x;
    const int t0 = q * SLICE;
    __shared__ float pl[SLICE + 2];
    __shared__ float ps[SLICE];
    __shared__ float part[4][Vn];
    __shared__ float red[4];

    float invp = 0.f;
    if (s > 0) invp = 1.f / psum_all[(s - 1) * Bn + b];
    const float* ap = out_attn + ((size_t)b * STEPSn + (s > 0 ? s - 1 : 0)) * Tn;
    for (int i = tid; i < SLICE + 2; i += 256) {
        int g = t0 - 1 + i;
        pl[i] = (s > 0 && g >= 0 && g < Tn) ? ap[g] : 0.f;
    }
    __syncthreads();

    const int t = t0 + tid;
    float left  = pl[tid]     * invp;
    float mid   = pl[tid + 1] * invp;
    float right = pl[tid + 2] * invp;

    float va[10];
    const float2* vp2 = (const float2*)vp + ((size_t)b * Tn + t) * 5;
    #pragma unroll
    for (int k = 0; k < 5; ++k) { float2 v2 = vp2[k]; va[2*k] = v2.x; va[2*k+1] = v2.y; }

    float ssum = score_b[0];
    #pragma unroll
    for (int a = 0; a < An; ++a) {
        float loc = conv_w[3*a]*left + conv_w[3*a+1]*mid + conv_w[3*a+2]*right + conv_b[a];
        float e = tanhf(qq_all[s * 16 + a] + va[a] + loc);
        ssum += score_w[a] * e;
    }
    float p = __expf(ssum);      // |score| <= |sb| + sum|score_w| ~ 0.7: safe without max
    ps[tid] = p;
    out_attn[((size_t)b * STEPSn + s) * Tn + t] = p;   // unnormalized; fixed at the end

    float wsum = waveReduceSum(p);
    if ((tid & 63) == 0) red[tid >> 6] = wsum;
    __syncthreads();
    if (tid == 0) atomicAdd(&psum_all[s * Bn + b], red[0] + red[1] + red[2] + red[3]);

    // unnormalized context partial over this slice
    const int lane = tid & 63, g4 = tid >> 6;
    float ax = 0.f, ay = 0.f;
    if (use16) {
        const unsigned int* e16 = (const unsigned int*)enc16 + ((size_t)b * Tn + t0) * 64 + lane;
        for (int r = g4; r < SLICE; r += 4) {
            float pw = ps[r];
            unsigned u = e16[(size_t)r * 64];
            ax = fmaf(pw, __uint_as_float(u << 16), ax);
            ay = fmaf(pw, __uint_as_float(u & 0xffff0000u), ay);
        }
    } else {
        const float2* e2 = (const float2*)(enc + ((size_t)b * Tn + t0) * Vn) + lane;
        for (int r = g4; r < SLICE; r += 4) {
            float pw = ps[r];
            float2 e = e2[(size_t)r * 64];
            ax = fmaf(pw, e.x, ax);
            ay = fmaf(pw, e.y, ay);
        }
    }
    part[g4][2 * lane]     = ax;
    part[g4][2 * lane + 1] = ay;
    __syncthreads();
    if (tid < Vn)
        atomicAdd(&ctx_all[((size_t)s * Bn + b) * Vn + tid],
                  part[0][tid] + part[1][tid] + part[2][tid] + part[3][tid]);
}

// ---------- batched MLP (per b,s): hcat -> y1 -> y2 ----------
__global__ __launch_bounds__(128) void mlp_kernel(
    const float* __restrict__ h1_all, const float* __restrict__ ctx_all,
    const float* __restrict__ psum_all,
    const float* __restrict__ fc_w1, const float* __restrict__ fc_b1,
    const float* __restrict__ fc_w2, const float* __restrict__ fc_b2,
    float* __restrict__ y2_all)
{
    const int bs = blockIdx.x;            // b*32 + s
    const int b = bs >> 5, s = bs & 31;
    const int tid = threadIdx.x;
    __shared__ float hcat[192], y1[96];
    float inv = 1.f / psum_all[s * Bn + b];
    if (tid < Hn) hcat[tid] = h1_all[s * Hn + tid];
    hcat[Hn + tid] = ctx_all[((size_t)s * Bn + b) * Vn + tid] * inv;
    __syncthreads();
    if (tid < 96) {
        float acc = fc_b1[tid];
        const float4* wr = (const float4*)(fc_w1 + tid * 192);
        #pragma unroll
        for (int k = 0; k < 48; ++k) {
            float4 w = wr[k];
            acc += w.x*hcat[4*k] + w.y*hcat[4*k+1] + w.z*hcat[4*k+2] + w.w*hcat[4*k+3];
        }
        y1[tid] = fmaxf(acc, 0.f);
    }
    __syncthreads();
    if (tid < 48) {
        float acc = fc_b2[tid];
        const float4* wr = (const float4*)(fc_w2 + tid * 96);
        #pragma unroll
        for (int k = 0; k < 24; ++k) {
            float4 w = wr[k];
            acc += w.x*y1[4*k] + w.y*y1[4*k+1] + w.z*y1[4*k+2] + w.w*y1[4*k+3];
        }
        y2_all[(size_t)bs * 48 + tid] = fmaxf(acc, 0.f);
    }
}

// ---------- logits for all 32 steps of one b (class-quarter per block) ----------
__global__ __launch_bounds__(256) void logit_kernel(
    const float* __restrict__ y2_all, const float* __restrict__ fc_w3,
    const float* __restrict__ fc_b3,
    float* __restrict__ esum_all, float* __restrict__ out_logp)
{
    const int b = blockIdx.x >> 2, q = blockIdx.x & 3;
    const int tid = threadIdx.x;
    __shared__ float y2s[STEPSn][48];
    __shared__ float es[STEPSn];
    for (int i = tid; i < STEPSn * 48; i += 256)
        ((float*)y2s)[i] = y2_all[(size_t)b * STEPSn * 48 + i];
    if (tid < STEPSn) es[tid] = 0.f;
    __syncthreads();

    float epart[STEPSn];
    #pragma unroll
    for (int s = 0; s < STEPSn; ++s) epart[s] = 0.f;

    for (int ci = 0; ci < 4; ++ci) {
        if (ci * 256 + tid < 1000) {
            int c = q * 1000 + ci * 256 + tid;
            float4 w[12];
            const float4* wr = (const float4*)(fc_w3 + (size_t)c * 48);
            #pragma unroll
            for (int j = 0; j < 12; ++j) w[j] = wr[j];
            float bias = fc_b3[c];
            #pragma unroll
            for (int s = 0; s < STEPSn; ++s) {
                float acc = bias;
                #pragma unroll
                for (int j = 0; j < 12; ++j) {
                    float4 ww = w[j];
                    acc += ww.x*y2s[s][4*j] + ww.y*y2s[s][4*j+1] + ww.z*y2s[s][4*j+2] + ww.w*y2s[s][4*j+3];
                }
                out_logp[((size_t)b * STEPSn + s) * NCn + c] = acc;  // raw logits; fixed later
                epart[s] += __expf(acc);   // |logits| ~ O(few): safe without max
            }
        }
    }
    #pragma unroll
    for (int s = 0; s < STEPSn; ++s) {
        float v = waveReduceSum(epart[s]);
        if ((tid & 63) == 0) atomicAdd(&es[s], v);
    }
    __syncthreads();
    if (tid < STEPSn) atomicAdd(&esum_all[b * STEPSn + tid], es[tid]);
}

// ---------- final: logp = raw - log(esum) ----------
__global__ __launch_bounds__(256) void fixlogp_kernel(float* __restrict__ out_logp,
                                                      const float* __restrict__ esum_all) {
    size_t idx4 = (size_t)blockIdx.x * 256 + threadIdx.x;
    int pair = (int)((idx4 * 4) / NCn);        // b*32 + s
    float lse = logf(esum_all[pair]);
    float4 v = ((float4*)out_logp)[idx4];
    v.x -= lse; v.y -= lse; v.z -= lse; v.w -= lse;
    ((float4*)out_logp)[idx4] = v;
}

// ---------- final: attn *= 1/psum ----------
__global__ __launch_bounds__(256) void normattn_kernel(float* __restrict__ out_attn,
                                                       const float* __restrict__ psum_all) {
    size_t idx4 = (size_t)blockIdx.x * 256 + threadIdx.x;
    int row = (int)((idx4 * 4) >> 11);         // b*32 + s
    int s = row & 31, b = row >> 5;
    float inv = 1.f / psum_all[s * Bn + b];
    float4 v = ((float4*)out_attn)[idx4];
    v.x *= inv; v.y *= inv; v.z *= inv; v.w *= inv;
    ((float4*)out_attn)[idx4] = v;
}

extern "C" void kernel_launch(void* const* d_in, const int* in_sizes, int n_in,
                              void* d_out, int out_size, void* d_ws, size_t ws_size,
                              hipStream_t stream) {
    const float* enc    = (const float*)d_in[0];
    // d_in[1] = rnn_w_ih0 — unused (x0 == 0)
    const float* w_hh0  = (const float*)d_in[2];
    const float* b_ih0  = (const float*)d_in[3];
    const float* b_hh0  = (const float*)d_in[4];
    const float* w_ih1  = (const float*)d_in[5];
    const float* w_hh1  = (const float*)d_in[6];
    const float* b_ih1  = (const float*)d_in[7];
    const float* b_hh1  = (const float*)d_in[8];
    const float* conv_w = (const float*)d_in[9];
    const float* conv_b = (const float*)d_in[10];
    const float* wq     = (const float*)d_in[11];
    const float* bq     = (const float*)d_in[12];
    const float* wv     = (const float*)d_in[13];
    const float* abias  = (const float*)d_in[14];
    const float* sw     = (const float*)d_in[15];
    const float* sb     = (const float*)d_in[16];
    const float* fc_w1  = (const float*)d_in[17];
    const float* fc_b1  = (const float*)d_in[18];
    const float* fc_w2  = (const float*)d_in[19];
    const float* fc_b2  = (const float*)d_in[20];
    const float* fc_w3  = (const float*)d_in[21];
    const float* fc_b3  = (const float*)d_in[22];

    // workspace layout (float units)
    size_t off_psum  = 0;                 size_t n_psum  = (size_t)STEPSn * Bn;        // 4096
    size_t off_esum  = off_psum + n_psum; size_t n_esum  = (size_t)Bn * STEPSn;        // 4096
    size_t off_ctx   = off_esum + n_esum; size_t n_ctx   = (size_t)STEPSn * Bn * Vn;   // 524288
    size_t off_h1    = off_ctx + n_ctx;   size_t n_h1    = (size_t)STEPSn * Hn;
    size_t off_qq    = off_h1 + n_h1;     size_t n_qq    = (size_t)STEPSn * 16;
    size_t off_y2    = off_qq + n_qq;     size_t n_y2    = (size_t)Bn * STEPSn * 48;
    size_t off_vp    = off_y2 + n_y2;     size_t n_vp    = (size_t)Bn * Tn * An;
    size_t off_e16   = off_vp + n_vp;     size_t n_e16_f = (size_t)Bn * Tn * Vn / 2;
    size_t need16    = (off_e16 + n_e16_f) * sizeof(float);

    float* wsf      = (float*)d_ws;
    float* psum_all = wsf + off_psum;
    float* esum_all = wsf + off_esum;
    float* ctx_all  = wsf + off_ctx;
    float* h1_all   = wsf + off_h1;
    float* qq_all   = wsf + off_qq;
    float* y2_all   = wsf + off_y2;
    float* vp       = wsf + off_vp;
    unsigned short* enc16 = (unsigned short*)(wsf + off_e16);
    int use16 = (ws_size >= need16) ? 1 : 0;

    float* out_logp = (float*)d_out;
    float* out_attn = out_logp + (size_t)Bn * STEPSn * NCn;

    // zero the accumulated buffers (psum, esum, ctx are contiguous)
    hipMemsetAsync(psum_all, 0, (n_psum + n_esum + n_ctx) * sizeof(float), stream);

    gru_traj_kernel<<<1, 256, 0, stream>>>(w_hh0, b_ih0, b_hh0, w_ih1, w_hh1, b_ih1, b_hh1,
                                           wq, bq, abias, h1_all, qq_all);
    vproj_kernel<<<(Bn * Tn * An + 255) / 256, 256, 0, stream>>>(enc, wv, vp);
    if (use16) {
        size_t nelem = (size_t)Bn * Tn * Vn;
        tobf16_kernel<<<(unsigned)(nelem / 4 / 256), 256, 0, stream>>>(enc, enc16);
    }

    for (int s = 0; s < STEPSn; ++s) {
        attn_step_kernel<<<Bn * NQ, 256, 0, stream>>>(
            enc, enc16, use16, vp, qq_all, conv_w, conv_b, sw, sb,
            psum_all, ctx_all, out_attn, s);
    }

    mlp_kernel<<<Bn * STEPSn, 128, 0, stream>>>(h1_all, ctx_all, psum_all,
                                                fc_w1, fc_b1, fc_w2, fc_b2, y2_all);
    logit_kernel<<<Bn * 4, 256, 0, stream>>>(y2_all, fc_w3, fc_b3, esum_all, out_logp);

    fixlogp_kernel<<<(unsigned)((size_t)Bn * STEPSn * NCn / 4 / 256), 256, 0, stream>>>(out_logp, esum_all);
    normattn_kernel<<<(unsigned)((size_t)Bn * STEPSn * Tn / 4 / 256), 256, 0, stream>>>(out_attn, psum_all);
}

// Round 4
// 949.609 us; speedup vs baseline: 3.8956x; 1.7789x over previous
//
#include <hip/hip_runtime.h>
#include <cstddef>

#define Bn 128
#define Tn 2048
#define Vn 128
#define An 10
#define Hn 64
#define NCn 4000
#define STEPSn 32
#define SCH 16          // steps per ctx block
#define TCH 512         // t per ctx block

__device__ __forceinline__ float waveReduceSum(float v) {
    #pragma unroll
    for (int off = 32; off > 0; off >>= 1) v += __shfl_xor(v, off, 64);
    return v;
}

__device__ __forceinline__ float ftanh(float x) {
    float e = __expf(2.f * x);
    return 1.f - __fdividef(2.f, e + 1.f);
}

__device__ __forceinline__ unsigned short f2bf(float f) {
    unsigned u = __float_as_uint(f);
    u += 0x7fffu + ((u >> 16) & 1u);
    return (unsigned short)(u >> 16);
}

// ---------- one-time: v_proj[(b*T+t)*A + a] ----------
__global__ __launch_bounds__(256) void vproj_kernel(const float* __restrict__ enc,
                                                    const float* __restrict__ wv,
                                                    float* __restrict__ vp) {
    int idx = blockIdx.x * 256 + threadIdx.x;
    if (idx >= Bn * Tn * An) return;
    int bt = idx / An;
    int a  = idx - bt * An;
    const float4* e = (const float4*)(enc + (size_t)bt * Vn);
    const float4* w = (const float4*)(wv + a * Vn);
    float acc = 0.f;
    #pragma unroll
    for (int k = 0; k < Vn / 4; ++k) {
        float4 ev = e[k], wvv = w[k];
        acc += ev.x * wvv.x + ev.y * wvv.y + ev.z * wvv.z + ev.w * wvv.w;
    }
    vp[idx] = acc;
}

// ---------- one-time: enc fp32 -> bf16 ----------
__global__ __launch_bounds__(256) void tobf16_kernel(const float* __restrict__ in,
                                                     unsigned short* __restrict__ out) {
    size_t i = ((size_t)blockIdx.x * 256 + threadIdx.x) * 4;
    float4 v = *(const float4*)(in + i);
    ushort4 o;
    o.x = f2bf(v.x); o.y = f2bf(v.y); o.z = f2bf(v.z); o.w = f2bf(v.w);
    *(ushort4*)(out + i) = o;
}

// ---------- one-time: GRU trajectory (attention-independent; x0 == 0) ----------
__global__ __launch_bounds__(256) void gru_traj_kernel(
    const float* __restrict__ w_hh0, const float* __restrict__ b_ih0, const float* __restrict__ b_hh0,
    const float* __restrict__ w_ih1, const float* __restrict__ w_hh1,
    const float* __restrict__ b_ih1, const float* __restrict__ b_hh1,
    const float* __restrict__ wq, const float* __restrict__ bq, const float* __restrict__ abias,
    float* __restrict__ h1_all, float* __restrict__ qq_all)
{
    __shared__ float h0[Hn], h1[Hn], h0n[Hn], h1n[Hn], g0[192], g1i[192], g1h[192];
    int tid = threadIdx.x;
    if (tid < Hn) { h0[tid] = 0.f; h1[tid] = 0.f; }
    __syncthreads();
    for (int s = 0; s < STEPSn; ++s) {
        if (tid < 192) {
            float acc = b_hh0[tid];
            const float4* wr = (const float4*)(w_hh0 + tid * Hn);
            #pragma unroll
            for (int k = 0; k < Hn / 4; ++k) {
                float4 w = wr[k];
                acc += w.x*h0[4*k] + w.y*h0[4*k+1] + w.z*h0[4*k+2] + w.w*h0[4*k+3];
            }
            g0[tid] = acc;
        }
        __syncthreads();
        if (tid < Hn) {
            float r = 1.f / (1.f + __expf(-(b_ih0[tid]      + g0[tid])));
            float z = 1.f / (1.f + __expf(-(b_ih0[64 + tid] + g0[64 + tid])));
            float n = tanhf(b_ih0[128 + tid] + r * g0[128 + tid]);
            h0n[tid] = (1.f - z) * n + z * h0[tid];
        }
        __syncthreads();
        if (tid < 192) {
            float acc = b_ih1[tid];
            const float4* wr = (const float4*)(w_ih1 + tid * Hn);
            #pragma unroll
            for (int k = 0; k < Hn / 4; ++k) {
                float4 w = wr[k];
                acc += w.x*h0n[4*k] + w.y*h0n[4*k+1] + w.z*h0n[4*k+2] + w.w*h0n[4*k+3];
            }
            g1i[tid] = acc;
            float acc2 = b_hh1[tid];
            const float4* wr2 = (const float4*)(w_hh1 + tid * Hn);
            #pragma unroll
            for (int k = 0; k < Hn / 4; ++k) {
                float4 w = wr2[k];
                acc2 += w.x*h1[4*k] + w.y*h1[4*k+1] + w.z*h1[4*k+2] + w.w*h1[4*k+3];
            }
            g1h[tid] = acc2;
        }
        __syncthreads();
        if (tid < Hn) {
            float r = 1.f / (1.f + __expf(-(g1i[tid]      + g1h[tid])));
            float z = 1.f / (1.f + __expf(-(g1i[64 + tid] + g1h[64 + tid])));
            float n = tanhf(g1i[128 + tid] + r * g1h[128 + tid]);
            h1n[tid] = (1.f - z) * n + z * h1[tid];
        }
        __syncthreads();
        if (tid < Hn) {
            h0[tid] = h0n[tid];
            float v = h1n[tid];
            h1[tid] = v;
            h1_all[s * Hn + tid] = v;
        }
        __syncthreads();
        if (tid < An) {
            float acc = bq[tid] + abias[tid];
            const float* wr = wq + tid * Hn;
            #pragma unroll
            for (int k = 0; k < Hn; ++k) acc += wr[k] * h1n[k];
            qq_all[s * 16 + tid] = acc;
        }
        __syncthreads();
    }
}

// ---------- ALL 32 steps, one block per b: score -> exp -> psum ----------
__global__ __launch_bounds__(1024) void score_chain_kernel(
    const float* __restrict__ vp, const float* __restrict__ qq_all,
    const float* __restrict__ conv_w, const float* __restrict__ conv_b,
    const float* __restrict__ score_w, const float* __restrict__ score_b,
    float* __restrict__ psum_all, float* __restrict__ out_attn)
{
    const int b = blockIdx.x;
    const int tid = threadIdx.x;
    __shared__ float la[2][Tn + 2];    // zero sentinels at [0] and [Tn+1]
    __shared__ float red[16];

    for (int i = tid; i < 2 * (Tn + 2); i += 1024) ((float*)la)[i] = 0.f;
    __syncthreads();

    float cw0[An], cw1[An], cw2[An], cb[An], sw[An];
    #pragma unroll
    for (int a = 0; a < An; ++a) {
        cw0[a] = conv_w[3*a]; cw1[a] = conv_w[3*a+1]; cw2[a] = conv_w[3*a+2];
        cb[a] = conv_b[a]; sw[a] = score_w[a];
    }
    const float sb = score_b[0];
    const float* vpb = vp + (size_t)b * Tn * An;
    float* oa = out_attn + (size_t)b * STEPSn * Tn;

    int cur = 0;
    float inv = 1.f;      // step 0: la is all zero anyway

    for (int s = 0; s < STEPSn; ++s) {
        float qa[An];
        #pragma unroll
        for (int a = 0; a < An; ++a) qa[a] = qq_all[s * 16 + a];

        const int nxt = cur ^ 1;
        float psum_loc = 0.f;
        #pragma unroll
        for (int half = 0; half < 2; ++half) {
            int t = tid + half * 1024;
            float l = la[cur][t]     * inv;
            float m = la[cur][t + 1] * inv;
            float r = la[cur][t + 2] * inv;
            float ssum = sb;
            const float2* vpt = (const float2*)(vpb + (size_t)t * An);
            #pragma unroll
            for (int k = 0; k < 5; ++k) {
                float2 v2 = vpt[k];
                int a0 = 2 * k, a1 = 2 * k + 1;
                float loc0 = cw0[a0]*l + cw1[a0]*m + cw2[a0]*r + cb[a0];
                float loc1 = cw0[a1]*l + cw1[a1]*m + cw2[a1]*r + cb[a1];
                ssum += sw[a0] * ftanh(qa[a0] + v2.x + loc0);
                ssum += sw[a1] * ftanh(qa[a1] + v2.y + loc1);
            }
            float p = __expf(ssum);    // |ssum| <~ 0.8: safe
            la[nxt][t + 1] = p;
            oa[(size_t)s * Tn + t] = p;            // unnormalized; ctx kernel fixes
            psum_loc += p;
        }
        // block reduce (16 waves)
        float wsum = waveReduceSum(psum_loc);
        __syncthreads();
        if ((tid & 63) == 0) red[tid >> 6] = wsum;
        __syncthreads();
        float tot = 0.f;
        #pragma unroll
        for (int i = 0; i < 16; ++i) tot += red[i];
        if (tid == 0) psum_all[b * STEPSn + s] = tot;
        inv = 1.f / tot;
        cur = nxt;
    }
}

// ---------- batched context + attn normalization ----------
// block = (b, tc, sc): ctx partial over t-chunk for 16 steps; writes normalized attn
__global__ __launch_bounds__(256) void ctx_kernel(
    const float* __restrict__ enc, const unsigned short* __restrict__ enc16, int use16,
    const float* __restrict__ psum_all,
    float* __restrict__ out_attn, float* __restrict__ pctx)
{
    const int bid = blockIdx.x;
    const int sc = bid & 1, tc = (bid >> 1) & 3, b = bid >> 3;
    const int t0 = tc * TCH, s0 = sc * SCH;
    const int tid = threadIdx.x;

    __shared__ float shbuf[SCH * TCH];      // Pn, then reused for partials
    __shared__ float invs[SCH];

    if (tid < SCH) invs[tid] = 1.f / psum_all[b * STEPSn + s0 + tid];
    __syncthreads();

    // load p, normalize, stash in LDS, write back normalized attn
    for (int i = tid; i < SCH * TCH; i += 256) {
        int si = i >> 9, ti = i & (TCH - 1);
        size_t gi = ((size_t)b * STEPSn + s0 + si) * Tn + t0 + ti;
        float p = out_attn[gi] * invs[si];
        shbuf[si * TCH + ti] = p;
        out_attn[gi] = p;
    }
    __syncthreads();

    const int lane = tid & 63, w = tid >> 6;
    float accx[SCH], accy[SCH];
    #pragma unroll
    for (int si = 0; si < SCH; ++si) { accx[si] = 0.f; accy[si] = 0.f; }

    for (int t4 = w * 4; t4 < TCH; t4 += 16) {
        float ex[4], ey[4];
        #pragma unroll
        for (int u = 0; u < 4; ++u) {
            if (use16) {
                unsigned uu = ((const unsigned*)enc16)[((size_t)b * Tn + t0 + t4 + u) * 64 + lane];
                ex[u] = __uint_as_float(uu << 16);
                ey[u] = __uint_as_float(uu & 0xffff0000u);
            } else {
                float2 e = ((const float2*)enc)[((size_t)b * Tn + t0 + t4 + u) * 64 + lane];
                ex[u] = e.x; ey[u] = e.y;
            }
        }
        #pragma unroll
        for (int si = 0; si < SCH; ++si) {
            float4 p4 = *(const float4*)&shbuf[si * TCH + t4];
            accx[si] = fmaf(p4.x, ex[0], accx[si]); accy[si] = fmaf(p4.x, ey[0], accy[si]);
            accx[si] = fmaf(p4.y, ex[1], accx[si]); accy[si] = fmaf(p4.y, ey[1], accy[si]);
            accx[si] = fmaf(p4.z, ex[2], accx[si]); accy[si] = fmaf(p4.z, ey[2], accy[si]);
            accx[si] = fmaf(p4.w, ex[3], accx[si]); accy[si] = fmaf(p4.w, ey[3], accy[si]);
        }
    }
    __syncthreads();     // done reading Pn
    #pragma unroll
    for (int si = 0; si < SCH; ++si) {
        shbuf[((w * SCH) + si) * Vn + 2 * lane]     = accx[si];
        shbuf[((w * SCH) + si) * Vn + 2 * lane + 1] = accy[si];
    }
    __syncthreads();
    for (int o = tid; o < SCH * Vn; o += 256) {
        int si = o >> 7, v = o & (Vn - 1);
        float s2 = shbuf[si * Vn + v] + shbuf[(SCH + si) * Vn + v]
                 + shbuf[(2 * SCH + si) * Vn + v] + shbuf[(3 * SCH + si) * Vn + v];
        pctx[(((size_t)b * STEPSn + s0 + si) * 4 + tc) * Vn + v] = s2;
    }
}

// ---------- batched MLP (per b,s) ----------
__global__ __launch_bounds__(128) void mlp_kernel(
    const float* __restrict__ h1_all, const float* __restrict__ pctx,
    const float* __restrict__ fc_w1, const float* __restrict__ fc_b1,
    const float* __restrict__ fc_w2, const float* __restrict__ fc_b2,
    float* __restrict__ y2_all)
{
    const int bs = blockIdx.x;            // b*32 + s
    const int s = bs & 31;
    const int tid = threadIdx.x;
    __shared__ float hcat[192], y1[96];
    if (tid < Hn) hcat[tid] = h1_all[s * Hn + tid];
    {
        const float* pc = pctx + (size_t)bs * 4 * Vn;
        hcat[Hn + tid] = pc[tid] + pc[Vn + tid] + pc[2 * Vn + tid] + pc[3 * Vn + tid];
    }
    __syncthreads();
    if (tid < 96) {
        float acc = fc_b1[tid];
        const float4* wr = (const float4*)(fc_w1 + tid * 192);
        #pragma unroll
        for (int k = 0; k < 48; ++k) {
            float4 w = wr[k];
            acc += w.x*hcat[4*k] + w.y*hcat[4*k+1] + w.z*hcat[4*k+2] + w.w*hcat[4*k+3];
        }
        y1[tid] = fmaxf(acc, 0.f);
    }
    __syncthreads();
    if (tid < 48) {
        float acc = fc_b2[tid];
        const float4* wr = (const float4*)(fc_w2 + tid * 96);
        #pragma unroll
        for (int k = 0; k < 24; ++k) {
            float4 w = wr[k];
            acc += w.x*y1[4*k] + w.y*y1[4*k+1] + w.z*y1[4*k+2] + w.w*y1[4*k+3];
        }
        y2_all[(size_t)bs * 48 + tid] = fmaxf(acc, 0.f);
    }
}

// ---------- logits: tiled GEMM  M=4096 (b,s) x N=4000 (classes), K=48 ----------
__global__ __launch_bounds__(256) void logit_kernel(
    const float* __restrict__ y2_all, const float* __restrict__ fc_w3,
    const float* __restrict__ fc_b3,
    float* __restrict__ esum_part, float* __restrict__ out_logp)
{
    const int gx = blockIdx.x;            // N-tile (32 tiles x 128)
    const int gy = blockIdx.y;            // M-tile (64 tiles x 64)
    const int tid = threadIdx.x;
    const int tx = tid & 31, ty = tid >> 5;
    const int gn = gx * 128, gm = gy * 64;

    __shared__ float y2s[64][52];
    __shared__ float w3s[128][52];
    __shared__ float bias[128];
    __shared__ float pes[64][33];

    for (int i = tid; i < 64 * 48; i += 256) {
        int r = i / 48, k = i - r * 48;
        y2s[r][k] = y2_all[(size_t)(gm + r) * 48 + k];
    }
    for (int i = tid; i < 128 * 48; i += 256) {
        int r = i / 48, k = i - r * 48;
        int c = gn + r;
        w3s[r][k] = (c < NCn) ? fc_w3[(size_t)c * 48 + k] : 0.f;
    }
    if (tid < 128) {
        int c = gn + tid;
        bias[tid] = (c < NCn) ? fc_b3[c] : 0.f;
    }
    __syncthreads();

    float acc[8][4];
    #pragma unroll
    for (int i = 0; i < 8; ++i)
        #pragma unroll
        for (int j = 0; j < 4; ++j) acc[i][j] = 0.f;

    #pragma unroll
    for (int k = 0; k < 48; k += 4) {
        float4 yv[8], wv[4];
        #pragma unroll
        for (int i = 0; i < 8; ++i) yv[i] = *(const float4*)&y2s[ty + 8 * i][k];
        #pragma unroll
        for (int j = 0; j < 4; ++j) wv[j] = *(const float4*)&w3s[tx + 32 * j][k];
        #pragma unroll
        for (int i = 0; i < 8; ++i)
            #pragma unroll
            for (int j = 0; j < 4; ++j)
                acc[i][j] += yv[i].x * wv[j].x + yv[i].y * wv[j].y
                           + yv[i].z * wv[j].z + yv[i].w * wv[j].w;
    }

    #pragma unroll
    for (int i = 0; i < 8; ++i) {
        int row = gm + ty + 8 * i;
        float ex = 0.f;
        #pragma unroll
        for (int j = 0; j < 4; ++j) {
            int c = gn + tx + 32 * j;
            if (c < NCn) {
                float lg = acc[i][j] + bias[tx + 32 * j];
                out_logp[(size_t)row * NCn + c] = lg;    // raw; lse subtracted later
                ex += __expf(lg);                         // |logit| small: no max
            }
        }
        pes[ty + 8 * i][tx] = ex;
    }
    __syncthreads();
    if (tid < 64) {
        float s2 = 0.f;
        #pragma unroll
        for (int x = 0; x < 32; ++x) s2 += pes[tid][x];
        esum_part[(size_t)(gm + tid) * 32 + gx] = s2;
    }
}

// ---------- lse[row] = log(sum of 32 partials) ----------
__global__ __launch_bounds__(256) void esum_reduce_kernel(const float* __restrict__ esum_part,
                                                          float* __restrict__ lse_all) {
    int row = blockIdx.x * 256 + threadIdx.x;
    if (row >= Bn * STEPSn) return;
    const float* p = esum_part + (size_t)row * 32;
    float s = 0.f;
    #pragma unroll
    for (int i = 0; i < 32; ++i) s += p[i];
    lse_all[row] = logf(s);
}

// ---------- final: logp = raw - lse ----------
__global__ __launch_bounds__(256) void fixlogp_kernel(float* __restrict__ out_logp,
                                                      const float* __restrict__ lse_all) {
    size_t idx4 = (size_t)blockIdx.x * 256 + threadIdx.x;
    int pair = (int)((idx4 * 4) / NCn);        // b*32 + s  (NCn % 4 == 0)
    float lse = lse_all[pair];
    float4 v = ((float4*)out_logp)[idx4];
    v.x -= lse; v.y -= lse; v.z -= lse; v.w -= lse;
    ((float4*)out_logp)[idx4] = v;
}

extern "C" void kernel_launch(void* const* d_in, const int* in_sizes, int n_in,
                              void* d_out, int out_size, void* d_ws, size_t ws_size,
                              hipStream_t stream) {
    const float* enc    = (const float*)d_in[0];
    // d_in[1] = rnn_w_ih0 — unused (x0 == 0)
    const float* w_hh0  = (const float*)d_in[2];
    const float* b_ih0  = (const float*)d_in[3];
    const float* b_hh0  = (const float*)d_in[4];
    const float* w_ih1  = (const float*)d_in[5];
    const float* w_hh1  = (const float*)d_in[6];
    const float* b_ih1  = (const float*)d_in[7];
    const float* b_hh1  = (const float*)d_in[8];
    const float* conv_w = (const float*)d_in[9];
    const float* conv_b = (const float*)d_in[10];
    const float* wq     = (const float*)d_in[11];
    const float* bq     = (const float*)d_in[12];
    const float* wv     = (const float*)d_in[13];
    const float* abias  = (const float*)d_in[14];
    const float* sw     = (const float*)d_in[15];
    const float* sb     = (const float*)d_in[16];
    const float* fc_w1  = (const float*)d_in[17];
    const float* fc_b1  = (const float*)d_in[18];
    const float* fc_w2  = (const float*)d_in[19];
    const float* fc_b2  = (const float*)d_in[20];
    const float* fc_w3  = (const float*)d_in[21];
    const float* fc_b3  = (const float*)d_in[22];

    // workspace layout (float units)
    size_t off = 0;
    float* wsf = (float*)d_ws;
    float* psum_all  = wsf + off; off += (size_t)Bn * STEPSn;
    float* lse_all   = wsf + off; off += (size_t)Bn * STEPSn;
    float* h1_all    = wsf + off; off += (size_t)STEPSn * Hn;
    float* qq_all    = wsf + off; off += (size_t)STEPSn * 16;
    float* y2_all    = wsf + off; off += (size_t)Bn * STEPSn * 48;
    float* esum_part = wsf + off; off += (size_t)Bn * STEPSn * 32;
    float* pctx      = wsf + off; off += (size_t)Bn * STEPSn * 4 * Vn;
    float* vp        = wsf + off; off += (size_t)Bn * Tn * An;
    unsigned short* enc16 = (unsigned short*)(wsf + off);
    size_t need16 = (off + (size_t)Bn * Tn * Vn / 2) * sizeof(float);
    int use16 = (ws_size >= need16) ? 1 : 0;

    float* out_logp = (float*)d_out;
    float* out_attn = out_logp + (size_t)Bn * STEPSn * NCn;

    gru_traj_kernel<<<1, 256, 0, stream>>>(w_hh0, b_ih0, b_hh0, w_ih1, w_hh1, b_ih1, b_hh1,
                                           wq, bq, abias, h1_all, qq_all);
    vproj_kernel<<<(Bn * Tn * An + 255) / 256, 256, 0, stream>>>(enc, wv, vp);
    if (use16) {
        size_t nelem = (size_t)Bn * Tn * Vn;
        tobf16_kernel<<<(unsigned)(nelem / 4 / 256), 256, 0, stream>>>(enc, enc16);
    }

    score_chain_kernel<<<Bn, 1024, 0, stream>>>(vp, qq_all, conv_w, conv_b, sw, sb,
                                                psum_all, out_attn);

    ctx_kernel<<<Bn * 4 * 2, 256, 0, stream>>>(enc, enc16, use16, psum_all, out_attn, pctx);

    mlp_kernel<<<Bn * STEPSn, 128, 0, stream>>>(h1_all, pctx, fc_w1, fc_b1, fc_w2, fc_b2, y2_all);

    logit_kernel<<<dim3(32, 64), 256, 0, stream>>>(y2_all, fc_w3, fc_b3, esum_part, out_logp);

    esum_reduce_kernel<<<(Bn * STEPSn + 255) / 256, 256, 0, stream>>>(esum_part, lse_all);

    fixlogp_kernel<<<(unsigned)((size_t)Bn * STEPSn * NCn / 4 / 256), 256, 0, stream>>>(out_logp, lse_all);
}

// Round 5
// 617.931 us; speedup vs baseline: 5.9865x; 1.5368x over previous
//
#include <hip/hip_runtime.h>
#include <cstddef>

#define Bn 128
#define Tn 2048
#define Vn 128
#define An 10
#define Hn 64
#define NCn 4000
#define STEPSn 32
#define SCH 16          // steps per ctx block
#define TCH 512         // t per ctx block
#define PREP_ROWS 64
#define NB_PREP ((Bn * Tn) / PREP_ROWS)   // 4096

__device__ __forceinline__ float waveReduceSum(float v) {
    #pragma unroll
    for (int off = 32; off > 0; off >>= 1) v += __shfl_xor(v, off, 64);
    return v;
}

__device__ __forceinline__ float ftanh(float x) {
    float e = __expf(2.f * x);
    return 1.f - __fdividef(2.f, e + 1.f);
}

__device__ __forceinline__ unsigned short f2bf(float f) {
    unsigned u = __float_as_uint(f);
    u += 0x7fffu + ((u >> 16) & 1u);
    return (unsigned short)(u >> 16);
}

// ---------- fused: enc->bf16 + v_proj(bf16) ; extra block does GRU trajectory ----------
__global__ __launch_bounds__(256) void prep_kernel(
    const float* __restrict__ enc, const float* __restrict__ wv,
    const float* __restrict__ w_hh0, const float* __restrict__ b_ih0, const float* __restrict__ b_hh0,
    const float* __restrict__ w_ih1, const float* __restrict__ w_hh1,
    const float* __restrict__ b_ih1, const float* __restrict__ b_hh1,
    const float* __restrict__ wq, const float* __restrict__ bq, const float* __restrict__ abias,
    unsigned short* __restrict__ enc16, unsigned short* __restrict__ vp16,
    float* __restrict__ h1_all, float* __restrict__ qq_all)
{
    const int tid = threadIdx.x;
    __shared__ float sh[PREP_ROWS][132];
    __shared__ float wvs[An][128];
    __shared__ float h0[Hn], h1[Hn], h0n[Hn], h1n[Hn], g0[192], g1i[192], g1h[192];

    if (blockIdx.x == NB_PREP) {
        // ---- GRU trajectory (x0 == 0 -> gi0 = b_ih0) ----
        if (tid < Hn) { h0[tid] = 0.f; h1[tid] = 0.f; }
        __syncthreads();
        for (int s = 0; s < STEPSn; ++s) {
            if (tid < 192) {
                float acc = b_hh0[tid];
                const float4* wr = (const float4*)(w_hh0 + tid * Hn);
                #pragma unroll
                for (int k = 0; k < Hn / 4; ++k) {
                    float4 w = wr[k];
                    acc += w.x*h0[4*k] + w.y*h0[4*k+1] + w.z*h0[4*k+2] + w.w*h0[4*k+3];
                }
                g0[tid] = acc;
            }
            __syncthreads();
            if (tid < Hn) {
                float r = 1.f / (1.f + __expf(-(b_ih0[tid]      + g0[tid])));
                float z = 1.f / (1.f + __expf(-(b_ih0[64 + tid] + g0[64 + tid])));
                float n = tanhf(b_ih0[128 + tid] + r * g0[128 + tid]);
                h0n[tid] = (1.f - z) * n + z * h0[tid];
            }
            __syncthreads();
            if (tid < 192) {
                float acc = b_ih1[tid];
                const float4* wr = (const float4*)(w_ih1 + tid * Hn);
                #pragma unroll
                for (int k = 0; k < Hn / 4; ++k) {
                    float4 w = wr[k];
                    acc += w.x*h0n[4*k] + w.y*h0n[4*k+1] + w.z*h0n[4*k+2] + w.w*h0n[4*k+3];
                }
                g1i[tid] = acc;
                float acc2 = b_hh1[tid];
                const float4* wr2 = (const float4*)(w_hh1 + tid * Hn);
                #pragma unroll
                for (int k = 0; k < Hn / 4; ++k) {
                    float4 w = wr2[k];
                    acc2 += w.x*h1[4*k] + w.y*h1[4*k+1] + w.z*h1[4*k+2] + w.w*h1[4*k+3];
                }
                g1h[tid] = acc2;
            }
            __syncthreads();
            if (tid < Hn) {
                float r = 1.f / (1.f + __expf(-(g1i[tid]      + g1h[tid])));
                float z = 1.f / (1.f + __expf(-(g1i[64 + tid] + g1h[64 + tid])));
                float n = tanhf(g1i[128 + tid] + r * g1h[128 + tid]);
                h1n[tid] = (1.f - z) * n + z * h1[tid];
            }
            __syncthreads();
            if (tid < Hn) {
                h0[tid] = h0n[tid];
                float v = h1n[tid];
                h1[tid] = v;
                h1_all[s * Hn + tid] = v;
            }
            __syncthreads();
            if (tid < An) {
                float acc = bq[tid] + abias[tid];
                const float* wr = wq + tid * Hn;
                #pragma unroll
                for (int k = 0; k < Hn; ++k) acc += wr[k] * h1n[k];
                qq_all[s * 16 + tid] = acc;
            }
            __syncthreads();
        }
        return;
    }

    // ---- enc -> bf16 + stage in LDS ----
    const size_t row0 = (size_t)blockIdx.x * PREP_ROWS;
    for (int i = tid; i < An * 32; i += 256) {
        int a = i >> 5, kq = i & 31;
        float4 w = ((const float4*)(wv + a * 128))[kq];
        *(float4*)&wvs[a][kq * 4] = w;
    }
    for (int i = tid; i < PREP_ROWS * 32; i += 256) {
        int r = i >> 5, kq = i & 31;
        float4 v = ((const float4*)(enc + (row0 + r) * 128))[kq];
        *(float4*)&sh[r][kq * 4] = v;
        ushort4 o;
        o.x = f2bf(v.x); o.y = f2bf(v.y); o.z = f2bf(v.z); o.w = f2bf(v.w);
        ((ushort4*)(enc16 + (row0 + r) * 128))[kq] = o;
    }
    __syncthreads();

    // ---- vp dots ----
    for (int i = tid; i < PREP_ROWS * An; i += 256) {
        int r = i / An, a = i - r * An;
        float acc = 0.f;
        #pragma unroll
        for (int k = 0; k < 128; k += 4) {
            float4 e = *(const float4*)&sh[r][k];
            float4 w = *(const float4*)&wvs[a][k];
            acc += e.x * w.x + e.y * w.y + e.z * w.z + e.w * w.w;
        }
        vp16[(row0 + r) * An + a] = f2bf(acc);
    }
}

// ---------- ALL 32 steps, one block per b: score -> exp -> psum -> normalized attn ----------
__global__ __launch_bounds__(1024) void score_chain_kernel(
    const unsigned short* __restrict__ vp16, const float* __restrict__ qq_all,
    const float* __restrict__ conv_w, const float* __restrict__ conv_b,
    const float* __restrict__ score_w, const float* __restrict__ score_b,
    float* __restrict__ psum_all, float* __restrict__ out_attn)
{
    const int b = blockIdx.x;
    const int tid = threadIdx.x;
    __shared__ float la[2][Tn + 2];    // zero sentinels at [0] and [Tn+1]
    __shared__ float red[16];

    for (int i = tid; i < 2 * (Tn + 2); i += 1024) ((float*)la)[i] = 0.f;
    __syncthreads();

    float cw0[An], cw1[An], cw2[An], cb[An], sw[An];
    #pragma unroll
    for (int a = 0; a < An; ++a) {
        cw0[a] = conv_w[3*a]; cw1[a] = conv_w[3*a+1]; cw2[a] = conv_w[3*a+2];
        cb[a] = conv_b[a]; sw[a] = score_w[a];
    }
    const float sb = score_b[0];
    const unsigned* vpb = (const unsigned*)(vp16 + (size_t)b * Tn * An);  // 5 uints / t
    float* oa = out_attn + (size_t)b * STEPSn * Tn;

    int cur = 0;
    float inv = 1.f;

    for (int s = 0; s < STEPSn; ++s) {
        float qa[An];
        #pragma unroll
        for (int a = 0; a < An; ++a) qa[a] = qq_all[s * 16 + a];

        const int nxt = cur ^ 1;
        float pv[2];
        float psum_loc = 0.f;
        #pragma unroll
        for (int half = 0; half < 2; ++half) {
            int t = tid + half * 1024;
            float l = la[cur][t]     * inv;
            float m = la[cur][t + 1] * inv;
            float r = la[cur][t + 2] * inv;
            float ssum = sb;
            const unsigned* vpt = vpb + (size_t)t * 5;
            #pragma unroll
            for (int k = 0; k < 5; ++k) {
                unsigned u = vpt[k];
                float v0 = __uint_as_float(u << 16);
                float v1 = __uint_as_float(u & 0xffff0000u);
                int a0 = 2 * k, a1 = 2 * k + 1;
                float loc0 = cw0[a0]*l + cw1[a0]*m + cw2[a0]*r + cb[a0];
                float loc1 = cw0[a1]*l + cw1[a1]*m + cw2[a1]*r + cb[a1];
                ssum += sw[a0] * ftanh(qa[a0] + v0 + loc0);
                ssum += sw[a1] * ftanh(qa[a1] + v1 + loc1);
            }
            float p = __expf(ssum);    // |ssum| <~ 0.8: safe without max
            la[nxt][t + 1] = p;
            pv[half] = p;
            psum_loc += p;
        }
        // block reduce (16 waves) — syncs also publish la[nxt]
        float wsum = waveReduceSum(psum_loc);
        __syncthreads();
        if ((tid & 63) == 0) red[tid >> 6] = wsum;
        __syncthreads();
        float tot = 0.f;
        #pragma unroll
        for (int i = 0; i < 16; ++i) tot += red[i];
        if (tid == 0) psum_all[b * STEPSn + s] = tot;
        inv = 1.f / tot;
        // normalized attention out (values held in registers)
        oa[(size_t)s * Tn + tid]        = pv[0] * inv;
        oa[(size_t)s * Tn + tid + 1024] = pv[1] * inv;
        cur = nxt;
    }
}

// ---------- batched context from normalized attn ----------
__global__ __launch_bounds__(256) void ctx_kernel(
    const unsigned short* __restrict__ enc16,
    const float* __restrict__ out_attn, float* __restrict__ pctx)
{
    const int bid = blockIdx.x;
    const int sc = bid & 1, tc = (bid >> 1) & 3, b = bid >> 3;
    const int t0 = tc * TCH, s0 = sc * SCH;
    const int tid = threadIdx.x;

    __shared__ float shbuf[SCH * TCH];      // attn slice, then reused for partials

    for (int i = tid; i < SCH * TCH; i += 256) {
        int si = i >> 9, ti = i & (TCH - 1);
        shbuf[si * TCH + ti] = out_attn[((size_t)b * STEPSn + s0 + si) * Tn + t0 + ti];
    }
    __syncthreads();

    const int lane = tid & 63, w = tid >> 6;
    float accx[SCH], accy[SCH];
    #pragma unroll
    for (int si = 0; si < SCH; ++si) { accx[si] = 0.f; accy[si] = 0.f; }

    for (int t4 = w * 4; t4 < TCH; t4 += 16) {
        float ex[4], ey[4];
        #pragma unroll
        for (int u = 0; u < 4; ++u) {
            unsigned uu = ((const unsigned*)enc16)[((size_t)b * Tn + t0 + t4 + u) * 64 + lane];
            ex[u] = __uint_as_float(uu << 16);
            ey[u] = __uint_as_float(uu & 0xffff0000u);
        }
        #pragma unroll
        for (int si = 0; si < SCH; ++si) {
            float4 p4 = *(const float4*)&shbuf[si * TCH + t4];
            accx[si] = fmaf(p4.x, ex[0], accx[si]); accy[si] = fmaf(p4.x, ey[0], accy[si]);
            accx[si] = fmaf(p4.y, ex[1], accx[si]); accy[si] = fmaf(p4.y, ey[1], accy[si]);
            accx[si] = fmaf(p4.z, ex[2], accx[si]); accy[si] = fmaf(p4.z, ey[2], accy[si]);
            accx[si] = fmaf(p4.w, ex[3], accx[si]); accy[si] = fmaf(p4.w, ey[3], accy[si]);
        }
    }
    __syncthreads();     // done reading attn slice
    #pragma unroll
    for (int si = 0; si < SCH; ++si) {
        shbuf[((w * SCH) + si) * Vn + 2 * lane]     = accx[si];
        shbuf[((w * SCH) + si) * Vn + 2 * lane + 1] = accy[si];
    }
    __syncthreads();
    for (int o = tid; o < SCH * Vn; o += 256) {
        int si = o >> 7, v = o & (Vn - 1);
        float s2 = shbuf[si * Vn + v] + shbuf[(SCH + si) * Vn + v]
                 + shbuf[(2 * SCH + si) * Vn + v] + shbuf[(3 * SCH + si) * Vn + v];
        pctx[(((size_t)b * STEPSn + s0 + si) * 4 + tc) * Vn + v] = s2;
    }
}

// ---------- batched MLP (per b,s) ----------
__global__ __launch_bounds__(128) void mlp_kernel(
    const float* __restrict__ h1_all, const float* __restrict__ pctx,
    const float* __restrict__ fc_w1, const float* __restrict__ fc_b1,
    const float* __restrict__ fc_w2, const float* __restrict__ fc_b2,
    float* __restrict__ y2_all)
{
    const int bs = blockIdx.x;            // b*32 + s
    const int s = bs & 31;
    const int tid = threadIdx.x;
    __shared__ float hcat[192], y1[96];
    if (tid < Hn) hcat[tid] = h1_all[s * Hn + tid];
    {
        const float* pc = pctx + (size_t)bs * 4 * Vn;
        hcat[Hn + tid] = pc[tid] + pc[Vn + tid] + pc[2 * Vn + tid] + pc[3 * Vn + tid];
    }
    __syncthreads();
    if (tid < 96) {
        float acc = fc_b1[tid];
        const float4* wr = (const float4*)(fc_w1 + tid * 192);
        #pragma unroll
        for (int k = 0; k < 48; ++k) {
            float4 w = wr[k];
            acc += w.x*hcat[4*k] + w.y*hcat[4*k+1] + w.z*hcat[4*k+2] + w.w*hcat[4*k+3];
        }
        y1[tid] = fmaxf(acc, 0.f);
    }
    __syncthreads();
    if (tid < 48) {
        float acc = fc_b2[tid];
        const float4* wr = (const float4*)(fc_w2 + tid * 96);
        #pragma unroll
        for (int k = 0; k < 24; ++k) {
            float4 w = wr[k];
            acc += w.x*y1[4*k] + w.y*y1[4*k+1] + w.z*y1[4*k+2] + w.w*y1[4*k+3];
        }
        y2_all[(size_t)bs * 48 + tid] = fmaxf(acc, 0.f);
    }
}

// ---------- logits GEMM: M=4096 x N=4000, K=48. 64x64 tile, 4x4 per thread ----------
__global__ __launch_bounds__(256) void logit_kernel(
    const float* __restrict__ y2_all, const float* __restrict__ fc_w3,
    const float* __restrict__ fc_b3,
    float* __restrict__ esum_part, float* __restrict__ out_logp)
{
    const int gx = blockIdx.x;            // N-tile: 63 tiles x 64
    const int gy = blockIdx.y;            // M-tile: 64 tiles x 64
    const int tid = threadIdx.x;
    const int tx = tid & 15, ty = tid >> 4;
    const int gn = gx * 64, gm = gy * 64;

    __shared__ float y2s[64][52];
    __shared__ float w3s[64][52];
    __shared__ float bias[64];

    for (int i = tid; i < 64 * 12; i += 256) {
        int r = i / 12, kq = i - r * 12;
        *(float4*)&y2s[r][kq * 4] = ((const float4*)(y2_all + (size_t)(gm + r) * 48))[kq];
    }
    for (int i = tid; i < 64 * 12; i += 256) {
        int r = i / 12, kq = i - r * 12;
        int c = gn + r;
        float4 w = (c < NCn) ? ((const float4*)(fc_w3 + (size_t)c * 48))[kq]
                             : make_float4(0.f, 0.f, 0.f, 0.f);
        *(float4*)&w3s[r][kq * 4] = w;
    }
    if (tid < 64) {
        int c = gn + tid;
        bias[tid] = (c < NCn) ? fc_b3[c] : 0.f;
    }
    __syncthreads();

    float acc[4][4];
    #pragma unroll
    for (int i = 0; i < 4; ++i)
        #pragma unroll
        for (int j = 0; j < 4; ++j) acc[i][j] = 0.f;

    #pragma unroll
    for (int k = 0; k < 48; k += 4) {
        float4 yv[4], wv[4];
        #pragma unroll
        for (int i = 0; i < 4; ++i) yv[i] = *(const float4*)&y2s[ty + 16 * i][k];
        #pragma unroll
        for (int j = 0; j < 4; ++j) wv[j] = *(const float4*)&w3s[tx + 16 * j][k];
        #pragma unroll
        for (int i = 0; i < 4; ++i)
            #pragma unroll
            for (int j = 0; j < 4; ++j)
                acc[i][j] += yv[i].x * wv[j].x + yv[i].y * wv[j].y
                           + yv[i].z * wv[j].z + yv[i].w * wv[j].w;
    }

    #pragma unroll
    for (int i = 0; i < 4; ++i) {
        int row = gm + ty + 16 * i;
        float ex = 0.f;
        #pragma unroll
        for (int j = 0; j < 4; ++j) {
            int c = gn + tx + 16 * j;
            if (c < NCn) {
                float lg = acc[i][j] + bias[tx + 16 * j];
                out_logp[(size_t)row * NCn + c] = lg;    // raw; lse subtracted later
                ex += __expf(lg);                         // |logit| small: no max
            }
        }
        // reduce across the 16 tx lanes (stay within wave for mask < 16)
        #pragma unroll
        for (int msk = 8; msk > 0; msk >>= 1) ex += __shfl_xor(ex, msk, 64);
        if (tx == 0) esum_part[(size_t)row * 64 + gx] = ex;
    }
}

// ---------- lse[row] = log(sum of 63 partials) ----------
__global__ __launch_bounds__(256) void esum_reduce_kernel(const float* __restrict__ esum_part,
                                                          float* __restrict__ lse_all) {
    int row = blockIdx.x * 256 + threadIdx.x;
    if (row >= Bn * STEPSn) return;
    const float* p = esum_part + (size_t)row * 64;
    float s = 0.f;
    #pragma unroll
    for (int i = 0; i < 63; ++i) s += p[i];
    lse_all[row] = logf(s);
}

// ---------- final: logp = raw - lse ----------
__global__ __launch_bounds__(256) void fixlogp_kernel(float* __restrict__ out_logp,
                                                      const float* __restrict__ lse_all) {
    size_t idx4 = (size_t)blockIdx.x * 256 + threadIdx.x;
    int pair = (int)((idx4 * 4) / NCn);        // NCn % 4 == 0: no row crossing
    float lse = lse_all[pair];
    float4 v = ((float4*)out_logp)[idx4];
    v.x -= lse; v.y -= lse; v.z -= lse; v.w -= lse;
    ((float4*)out_logp)[idx4] = v;
}

extern "C" void kernel_launch(void* const* d_in, const int* in_sizes, int n_in,
                              void* d_out, int out_size, void* d_ws, size_t ws_size,
                              hipStream_t stream) {
    const float* enc    = (const float*)d_in[0];
    // d_in[1] = rnn_w_ih0 — unused (x0 == 0)
    const float* w_hh0  = (const float*)d_in[2];
    const float* b_ih0  = (const float*)d_in[3];
    const float* b_hh0  = (const float*)d_in[4];
    const float* w_ih1  = (const float*)d_in[5];
    const float* w_hh1  = (const float*)d_in[6];
    const float* b_ih1  = (const float*)d_in[7];
    const float* b_hh1  = (const float*)d_in[8];
    const float* conv_w = (const float*)d_in[9];
    const float* conv_b = (const float*)d_in[10];
    const float* wq     = (const float*)d_in[11];
    const float* bq     = (const float*)d_in[12];
    const float* wv     = (const float*)d_in[13];
    const float* abias  = (const float*)d_in[14];
    const float* sw     = (const float*)d_in[15];
    const float* sb     = (const float*)d_in[16];
    const float* fc_w1  = (const float*)d_in[17];
    const float* fc_b1  = (const float*)d_in[18];
    const float* fc_w2  = (const float*)d_in[19];
    const float* fc_b2  = (const float*)d_in[20];
    const float* fc_w3  = (const float*)d_in[21];
    const float* fc_b3  = (const float*)d_in[22];

    // workspace layout (float units)
    size_t off = 0;
    float* wsf = (float*)d_ws;
    float* psum_all  = wsf + off; off += (size_t)Bn * STEPSn;
    float* lse_all   = wsf + off; off += (size_t)Bn * STEPSn;
    float* h1_all    = wsf + off; off += (size_t)STEPSn * Hn;
    float* qq_all    = wsf + off; off += (size_t)STEPSn * 16;
    float* y2_all    = wsf + off; off += (size_t)Bn * STEPSn * 48;
    float* esum_part = wsf + off; off += (size_t)Bn * STEPSn * 64;
    float* pctx      = wsf + off; off += (size_t)Bn * STEPSn * 4 * Vn;
    unsigned short* vp16  = (unsigned short*)(wsf + off); off += (size_t)Bn * Tn * An / 2;
    unsigned short* enc16 = (unsigned short*)(wsf + off); off += (size_t)Bn * Tn * Vn / 2;

    float* out_logp = (float*)d_out;
    float* out_attn = out_logp + (size_t)Bn * STEPSn * NCn;

    prep_kernel<<<NB_PREP + 1, 256, 0, stream>>>(
        enc, wv, w_hh0, b_ih0, b_hh0, w_ih1, w_hh1, b_ih1, b_hh1,
        wq, bq, abias, enc16, vp16, h1_all, qq_all);

    score_chain_kernel<<<Bn, 1024, 0, stream>>>(vp16, qq_all, conv_w, conv_b, sw, sb,
                                                psum_all, out_attn);

    ctx_kernel<<<Bn * 4 * 2, 256, 0, stream>>>(enc16, out_attn, pctx);

    mlp_kernel<<<Bn * STEPSn, 128, 0, stream>>>(h1_all, pctx, fc_w1, fc_b1, fc_w2, fc_b2, y2_all);

    logit_kernel<<<dim3(63, 64), 256, 0, stream>>>(y2_all, fc_w3, fc_b3, esum_part, out_logp);

    esum_reduce_kernel<<<(Bn * STEPSn + 255) / 256, 256, 0, stream>>>(esum_part, lse_all);

    fixlogp_kernel<<<(unsigned)((size_t)Bn * STEPSn * NCn / 4 / 256), 256, 0, stream>>>(out_logp, lse_all);
}